// Round 2
// baseline (7531.579 us; speedup 1.0000x reference)
//
#include <hip/hip_runtime.h>
#include <stdint.h>

// ======================= Problem constants =======================
// fp32 dataset (per harness contract: dtypes follow the reference).
// edge_index arrives as int32 (harness converts int64 -> int32).
// Compute in bf16 MFMA (tolerance is bf16-grade), I/O in f32.
#define NN 25000
#define NE 400000

using u16  = unsigned short;
using u32t = unsigned int;

typedef __attribute__((ext_vector_type(8)))  short s8v;   // 8 x bf16 (4 VGPR) MFMA A/B frag
typedef __attribute__((ext_vector_type(16))) float f16v;  // 32x32 MFMA accumulator

// ---------------- workspace layout (bytes) ----------------
#define OFF_FBF_B  (524288)                 // f (node embed) bf16 [25000][128]
#define OFF_AGG_B  (6924288)                // agg f32 [25000][128]
#define WS_NEED    (19724288)

// ---------------- transposed-weight blob offsets (u16 units) ----------------
#define OWA   0
#define OWB1  16384
#define OWB2  32768
#define OWS1  49152
#define OWS2  98304
#define OWH1  114688
#define OWH2  147456
#define OWV1  163840
#define OWV2  212992
#define OWT1  229376
#define OWT2  245760

static __device__ __forceinline__ float bf2f(u16 v){
  u32t x = ((u32t)v) << 16; float f; __builtin_memcpy(&f, &x, 4); return f;
}
static __device__ __forceinline__ u16 f2bf(float f){
  u32t x; __builtin_memcpy(&x, &f, 4);
  return (u16)((x + 0x7FFFu + ((x >> 16) & 1u)) >> 16);   // RNE
}

static __device__ __forceinline__ void zacc(f16v* acc){
#pragma unroll
  for (int i = 0; i < 16; ++i){ acc[0][i] = 0.f; acc[1][i] = 0.f; }
}

// GEMM: [64 rows x 32 cols-per-wave] += A[64][K] @ W[K][128], bf16 MFMA.
// A in LDS (padded stride, u16 units); W^T[N=128][Kp] row-major bf16 in global (L2-hot).
// A-frag: row = lane&31, k = 8*(lane>>5)+j.  B-frag: col = lane&31, same k.
template<int K>
static __device__ __forceinline__ void gemm64(const u16* A, int astride, int aofs,
                                              const u16* __restrict__ WT, int Kp,
                                              int lane, int ct, f16v* acc)
{
  const int col = ct * 32 + (lane & 31);
  const int kh  = (lane >> 5) * 8;
  const u16* __restrict__ w  = WT + (size_t)col * Kp + kh;
  const u16* a0 = A + (lane & 31) * astride + aofs + kh;
  const u16* a1 = a0 + 32 * astride;
#pragma unroll 2
  for (int k = 0; k < K; k += 16){
    s8v b  = *(const s8v*)(w + k);
    s8v x0 = *(const s8v*)(a0 + k);
    s8v x1 = *(const s8v*)(a1 + k);
    acc[0] = __builtin_amdgcn_mfma_f32_32x32x16_bf16(x0, b, acc[0], 0, 0, 0);
    acc[1] = __builtin_amdgcn_mfma_f32_32x32x16_bf16(x1, b, acc[1], 0, 0, 0);
  }
}

// C/D layout: col = lane&31, row = (reg&3)+8*(reg>>2)+4*(lane>>5)  (+32 for acc[1])
static __device__ __forceinline__ void store_acc(const f16v* acc, u16* dst, int dstride, int dofs,
                                                 const float* __restrict__ bias, int act,
                                                 int lane, int ct)
{
  const int col = ct * 32 + (lane & 31);
  const float b = bias[col];
#pragma unroll
  for (int rt = 0; rt < 2; ++rt){
#pragma unroll
    for (int r = 0; r < 16; ++r){
      float x = acc[rt][r] + b;
      if (act) x = x / (1.f + __expf(-x));        // SiLU
      const int row = rt * 32 + (r & 3) + 8 * (r >> 2) + 4 * (lane >> 5);
      dst[row * dstride + dofs + col] = f2bf(x);
    }
  }
}

// ======================= weight prep: f32 W[K][128] -> bf16 W^T[128][Kp] =======================
struct WDesc { const float* src; int K; int dstoff; int Kp; };
struct WTab  { WDesc w[11]; };

__global__ void k_prep(WTab tab, u16* __restrict__ WT)
{
  const WDesc d = tab.w[blockIdx.y];
  const int total = 128 * d.Kp;
  const int idx = blockIdx.x * 256 + threadIdx.x;
  if (idx >= total) return;
  const int n = idx / d.Kp;
  const int k = idx - n * d.Kp;
  WT[d.dstoff + idx] = (k < d.K) ? f2bf(d.src[(size_t)k * 128 + n]) : (u16)0;
}

// ======================= f = species @ Wa + ba  (f stored bf16 in ws) =======================
__global__ void __launch_bounds__(256, 2) k_f(const float* __restrict__ species,
                                              const u16* __restrict__ WT,
                                              const float* __restrict__ ba,
                                              u16* __restrict__ fbf)
{
  __shared__ u16 S[64 * 136];
  __shared__ u16 H[64 * 136];
  const int tid = threadIdx.x, lane = tid & 63, wid = tid >> 6;
  const int n0 = blockIdx.x * 64;
  const int rem = (NN - n0) < 64 ? (NN - n0) : 64;
  {
    const int row = tid >> 2, sub = tid & 3;
    const bool ok = row < rem;
    const float* src = species + (size_t)(n0 + row) * 100;
    for (int c = sub * 32; c < sub * 32 + 32; ++c)
      S[row * 136 + c] = (ok && c < 100) ? f2bf(src[c]) : (u16)0;
  }
  __syncthreads();
  f16v acc[2];
  zacc(acc);
  gemm64<128>(S, 136, 0, WT + OWA, 128, lane, wid, acc);
  store_acc(acc, H, 136, 0, ba, 0, lane, wid);
  __syncthreads();
#pragma unroll
  for (int it = 0; it < 8; ++it){
    const int row = it * 8 + (tid >> 5);
    if (row < rem){
      const int c4 = (tid & 31) * 4;
      uint2 v = *(const uint2*)(&H[row * 136 + c4]);
      *(uint2*)(fbf + (size_t)(n0 + row) * 128 + c4) = v;
    }
  }
}

// ======================= edge kernel =======================
// Per block: 64 edges. LDS E = [64][392]: cols 0-127 f_i, 128-255 f_j, 256-383 X0/ea.
__global__ void __launch_bounds__(256, 2) k_edge(
    const u16* __restrict__ fbf, const int* __restrict__ eidx,
    const float* __restrict__ eattr, const float* __restrict__ evec,
    const u16* __restrict__ WT,
    const float* __restrict__ bb1, const float* __restrict__ bb2,
    const float* __restrict__ bs1, const float* __restrict__ bs2,
    const float* __restrict__ bv1, const float* __restrict__ bv2,
    float* __restrict__ ea_out, float* __restrict__ agg, float* __restrict__ v0out)
{
  __shared__ u16 E[64 * 392];
  __shared__ u16 H[64 * 136];
  const int tid = threadIdx.x, lane = tid & 63, wid = tid >> 6;
  const int e0 = blockIdx.x * 64;

  // ---- stage f_i, f_j (bf16 gather), X0 = f2bf(edge_attr) (pad 120->128 zeros)
  {
    const int row = tid >> 2, sub = tid & 3;
    const int ii = eidx[e0 + row];
    const int jj = eidx[NE + e0 + row];
    const uint4* si = (const uint4*)(fbf + (size_t)ii * 128 + sub * 32);
    const uint4* sj = (const uint4*)(fbf + (size_t)jj * 128 + sub * 32);
    uint4* di = (uint4*)(&E[row * 392 + sub * 32]);
    uint4* dj = (uint4*)(&E[row * 392 + 128 + sub * 32]);
#pragma unroll
    for (int q = 0; q < 4; ++q){ di[q] = si[q]; dj[q] = sj[q]; }
  }
  if (tid < 128){
    const int row = tid >> 1, u = tid & 1;
    const float* s = eattr + (size_t)(e0 + row) * 120 + u * 60;
#pragma unroll
    for (int q = 0; q < 15; ++q){
      float4 v = *(const float4*)(s + q * 4);
      ushort4 p;
      p.x = f2bf(v.x); p.y = f2bf(v.y); p.z = f2bf(v.z); p.w = f2bf(v.w);
      *(ushort4*)(&E[row * 392 + 256 + u * 60 + q * 4]) = p;
    }
    ushort4 z; z.x = z.y = z.z = z.w = 0;
    *(ushort4*)(&E[row * 392 + 376 + u * 4]) = z;
  }
  __syncthreads();

  f16v acc[2];

  // ---- ea = silu(X0@Wb1+bb1)@Wb2 + bb2
  zacc(acc);
  gemm64<128>(E, 392, 256, WT + OWB1, 128, lane, wid, acc);
  store_acc(acc, H, 136, 0, bb1, 1, lane, wid);
  __syncthreads();
  zacc(acc);
  gemm64<128>(H, 136, 0, WT + OWB2, 128, lane, wid, acc);
  __syncthreads();                                   // all done reading H & X0
  store_acc(acc, E, 392, 256, bb2, 0, lane, wid);    // ea (bf16) into E[:,256:384]
  __syncthreads();
#pragma unroll
  for (int it = 0; it < 8; ++it){                    // ea -> global f32 (coalesced)
    const int row = it * 8 + (tid >> 5);
    const int c4 = (tid & 31) * 4;
    uint2 v = *(const uint2*)(&E[row * 392 + 256 + c4]);
    const u16* hp = (const u16*)&v;
    float4 o;
    o.x = bf2f(hp[0]); o.y = bf2f(hp[1]); o.z = bf2f(hp[2]); o.w = bf2f(hp[3]);
    *(float4*)(ea_out + (size_t)(e0 + row) * 128 + c4) = o;
  }

  // ---- msg = (silu(e@Ws1+bs1)@Ws2+bs2) * f_i ; agg[j] += msg
  zacc(acc);
  gemm64<384>(E, 392, 0, WT + OWS1, 384, lane, wid, acc);
  store_acc(acc, H, 136, 0, bs1, 1, lane, wid);
  __syncthreads();
  zacc(acc);
  gemm64<128>(H, 136, 0, WT + OWS2, 128, lane, wid, acc);
  __syncthreads();
  store_acc(acc, H, 136, 0, bs2, 0, lane, wid);
  __syncthreads();
#pragma unroll
  for (int it = 0; it < 8; ++it){
    const int row = it * 8 + (tid >> 5);
    const int c4 = (tid & 31) * 4;
    const int jj = eidx[NE + e0 + row];
    uint2 hm = *(const uint2*)(&H[row * 136 + c4]);
    uint2 fi = *(const uint2*)(&E[row * 392 + c4]);
    const u16* hp = (const u16*)&hm;
    const u16* fp = (const u16*)&fi;
    float* base = agg + (size_t)jj * 128 + c4;
#pragma unroll
    for (int q = 0; q < 4; ++q)
      atomicAdd(base + q, bf2f(hp[q]) * bf2f(fp[q]));
  }
  __syncthreads();

  // ---- mv = silu(e@Wv1+bv1)@Wv2+bv2 ; v0[j,d,x] += edge_vec[e,x]*mv[e,d]
  zacc(acc);
  gemm64<384>(E, 392, 0, WT + OWV1, 384, lane, wid, acc);
  store_acc(acc, H, 136, 0, bv1, 1, lane, wid);
  __syncthreads();
  zacc(acc);
  gemm64<128>(H, 136, 0, WT + OWV2, 128, lane, wid, acc);
  __syncthreads();
  store_acc(acc, H, 136, 0, bv2, 0, lane, wid);
  __syncthreads();
#pragma unroll
  for (int it = 0; it < 8; ++it){
    const int row = it * 8 + (tid >> 5);
    const int c4 = (tid & 31) * 4;
    const int e = e0 + row;
    const int jj = eidx[NE + e];
    const float w0 = evec[(size_t)e * 3 + 0];
    const float w1 = evec[(size_t)e * 3 + 1];
    const float w2 = evec[(size_t)e * 3 + 2];
    uint2 hm = *(const uint2*)(&H[row * 136 + c4]);
    const u16* hp = (const u16*)&hm;
    float* base = v0out + (size_t)jj * 384 + (size_t)c4 * 3;
#pragma unroll
    for (int q = 0; q < 4; ++q){
      const float m = bf2f(hp[q]);
      atomicAdd(base + q * 3 + 0, m * w0);
      atomicAdd(base + q * 3 + 1, m * w1);
      atomicAdd(base + q * 3 + 2, m * w2);
    }
  }
}

// ======================= node kernel: h0 =======================
__global__ void __launch_bounds__(256, 2) k_node(
    const u16* __restrict__ fbf, const float* __restrict__ agg,
    const float* __restrict__ tin, const float* __restrict__ brff,
    const u16* __restrict__ WT,
    const float* __restrict__ bh1, const float* __restrict__ bh2,
    const float* __restrict__ bt1, const float* __restrict__ bt2,
    float* __restrict__ out)
{
  __shared__ u16 E2[64 * 264];   // [f | agg]
  __shared__ u16 RF[64 * 136];   // rff = [cos | sin]
  __shared__ u16 H[64 * 136];
  const int tid = threadIdx.x, lane = tid & 63, wid = tid >> 6;
  const int n0 = blockIdx.x * 64;
  const int rem = (NN - n0) < 64 ? (NN - n0) : 64;

  {
    const int row = tid >> 2, sub = tid & 3;
    if (row < rem){
      const uint4* s = (const uint4*)(fbf + (size_t)(n0 + row) * 128 + sub * 32);
      uint4* d = (uint4*)(&E2[row * 264 + sub * 32]);
#pragma unroll
      for (int q = 0; q < 4; ++q) d[q] = s[q];
      const float4* ag = (const float4*)(agg + (size_t)(n0 + row) * 128 + sub * 32);
#pragma unroll
      for (int q = 0; q < 8; ++q){
        float4 v = ag[q];
        ushort4 p;
        p.x = f2bf(v.x); p.y = f2bf(v.y); p.z = f2bf(v.z); p.w = f2bf(v.w);
        *(ushort4*)(&E2[row * 264 + 128 + sub * 32 + q * 4]) = p;
      }
    } else {
      uint4 z; z.x = z.y = z.z = z.w = 0;
      uint4* d  = (uint4*)(&E2[row * 264 + sub * 32]);
      uint4* d2 = (uint4*)(&E2[row * 264 + 128 + sub * 32]);
#pragma unroll
      for (int q = 0; q < 4; ++q){ d[q] = z; d2[q] = z; }
    }
  }
  {
    const int row = tid >> 2, qq = tid & 3;
    if (row < rem){
      const float tv = tin[n0 + row];
      for (int c = qq * 16; c < qq * 16 + 16; ++c){
        const float p = 6.283185307179586f * tv * brff[c];
        RF[row * 136 + c]      = f2bf(cosf(p));
        RF[row * 136 + 64 + c] = f2bf(sinf(p));
      }
    } else {
      for (int c = qq * 16; c < qq * 16 + 16; ++c){
        RF[row * 136 + c] = 0; RF[row * 136 + 64 + c] = 0;
      }
    }
  }
  __syncthreads();

  f16v acc[2], acch[2];
  zacc(acc);
  gemm64<256>(E2, 264, 0, WT + OWH1, 256, lane, wid, acc);
  store_acc(acc, H, 136, 0, bh1, 1, lane, wid);
  __syncthreads();
  zacc(acch);
  gemm64<128>(H, 136, 0, WT + OWH2, 128, lane, wid, acch);
  __syncthreads();
  zacc(acc);
  gemm64<128>(RF, 136, 0, WT + OWT1, 128, lane, wid, acc);
  store_acc(acc, H, 136, 0, bt1, 1, lane, wid);
  __syncthreads();
  gemm64<128>(H, 136, 0, WT + OWT2, 128, lane, wid, acch);  // accumulate
  __syncthreads();
  {
    const int col = wid * 32 + (lane & 31);
    const float b = bh2[col] + bt2[col];
#pragma unroll
    for (int rt = 0; rt < 2; ++rt)
#pragma unroll
      for (int r = 0; r < 16; ++r){
        const int row = rt * 32 + (r & 3) + 8 * (r >> 2) + 4 * (lane >> 5);
        H[row * 136 + col] = f2bf(acch[rt][r] + b);
      }
  }
  __syncthreads();
#pragma unroll
  for (int it = 0; it < 8; ++it){
    const int row = it * 8 + (tid >> 5);
    if (row < rem){
      const int c4 = (tid & 31) * 4;
      uint2 v = *(const uint2*)(&H[row * 136 + c4]);
      const u16* hp = (const u16*)&v;
      float4 o;
      o.x = bf2f(hp[0]); o.y = bf2f(hp[1]); o.z = bf2f(hp[2]); o.w = bf2f(hp[3]);
      *(float4*)(out + (size_t)(n0 + row) * 128 + c4) = o;
    }
  }
}

// ======================= launcher =======================
extern "C" void kernel_launch(void* const* d_in, const int* in_sizes, int n_in,
                              void* d_out, int out_size, void* d_ws, size_t ws_size,
                              hipStream_t stream)
{
  (void)in_sizes; (void)n_in; (void)out_size;
  const float* species = (const float*)d_in[0];
  const int*   eidx    = (const int*)d_in[1];
  const float* eattr   = (const float*)d_in[2];
  const float* evec    = (const float*)d_in[3];
  const float* tin     = (const float*)d_in[4];
  const float* Wa  = (const float*)d_in[5];  const float* ba  = (const float*)d_in[6];
  const float* Wb1 = (const float*)d_in[7];  const float* bb1 = (const float*)d_in[8];
  const float* Wb2 = (const float*)d_in[9];  const float* bb2 = (const float*)d_in[10];
  const float* Ws1 = (const float*)d_in[11]; const float* bs1 = (const float*)d_in[12];
  const float* Ws2 = (const float*)d_in[13]; const float* bs2 = (const float*)d_in[14];
  const float* Wh1 = (const float*)d_in[15]; const float* bh1 = (const float*)d_in[16];
  const float* Wh2 = (const float*)d_in[17]; const float* bh2 = (const float*)d_in[18];
  const float* Wv1 = (const float*)d_in[19]; const float* bv1 = (const float*)d_in[20];
  const float* Wv2 = (const float*)d_in[21]; const float* bv2 = (const float*)d_in[22];
  const float* brff= (const float*)d_in[23];
  const float* Wt1 = (const float*)d_in[24]; const float* bt1 = (const float*)d_in[25];
  const float* Wt2 = (const float*)d_in[26]; const float* bt2 = (const float*)d_in[27];

  if (ws_size < (size_t)WS_NEED) return;

  u16*   WT  = (u16*)d_ws;
  u16*   fbf = (u16*)((char*)d_ws + OFF_FBF_B);
  float* agg = (float*)((char*)d_ws + OFF_AGG_B);
  float* out = (float*)d_out;
  float* v0  = out + 3200000;        // v0 accumulated directly in d_out (f32)
  float* eao = out + 12800000;       // ea region

  // zero accumulators (ws/out are re-poisoned before every call)
  hipMemsetAsync((char*)d_ws + OFF_AGG_B, 0, 12800000, stream);
  hipMemsetAsync((void*)v0, 0, 38400000, stream);

  WTab tab;
  tab.w[0]  = { Wa , 100, OWA , 128 };
  tab.w[1]  = { Wb1, 120, OWB1, 128 };
  tab.w[2]  = { Wb2, 128, OWB2, 128 };
  tab.w[3]  = { Ws1, 384, OWS1, 384 };
  tab.w[4]  = { Ws2, 128, OWS2, 128 };
  tab.w[5]  = { Wh1, 256, OWH1, 256 };
  tab.w[6]  = { Wh2, 128, OWH2, 128 };
  tab.w[7]  = { Wv1, 384, OWV1, 384 };
  tab.w[8]  = { Wv2, 128, OWV2, 128 };
  tab.w[9]  = { Wt1, 128, OWT1, 128 };
  tab.w[10] = { Wt2, 128, OWT2, 128 };
  hipLaunchKernelGGL(k_prep, dim3(192, 11), dim3(256), 0, stream, tab, WT);

  hipLaunchKernelGGL(k_f,    dim3(391),  dim3(256), 0, stream, species, WT, ba, fbf);
  hipLaunchKernelGGL(k_edge, dim3(6250), dim3(256), 0, stream,
                     fbf, eidx, eattr, evec, WT, bb1, bb2, bs1, bs2, bv1, bv2,
                     eao, agg, v0);
  hipLaunchKernelGGL(k_node, dim3(391),  dim3(256), 0, stream,
                     fbf, agg, tin, brff, WT, bh1, bh2, bt1, bt2, out);
}

// Round 3
// 1004.013 us; speedup vs baseline: 7.5015x; 7.5015x over previous
//
#include <hip/hip_runtime.h>
#include <stdint.h>

// ======================= Problem constants =======================
// fp32 dataset; edge_index as int32. Compute in bf16 MFMA, I/O f32.
#define NN 25000
#define NE 400000

using u16  = unsigned short;
using u32t = unsigned int;

typedef __attribute__((ext_vector_type(8)))  short s8v;   // 8 x bf16 MFMA A/B frag
typedef __attribute__((ext_vector_type(16))) float f16v;  // 32x32 MFMA accumulator

// ---------------- workspace layout (bytes) ----------------
#define OFF_FBF_B  (524288)      // f bf16 [25000][128]
#define OFF_AGG_B  (6924288)     // agg bf16 [25000][128]
#define OFF_PTR_B  (13324288)    // CSR row ptr, 25001 ints
#define OFF_TAIL_B (13424384)    // counts/tails, 25000 ints
#define OFF_PERM_B (13524480)    // edge permutation, 400000 ints
#define WS_NEED    (15200000)

// d_out layout (floats): h0 [0,3.2M) | v0 [3.2M,12.8M) | ea [12.8M,64M)
// msg bf16 scratch = ea floats [12.8M,38.4M); mv bf16 = ea floats [38.4M,64M)

// ---------------- transposed-weight blob offsets (u16 units) ----------------
#define OWA   0
#define OWB1  16384
#define OWB2  32768
#define OWS1  49152
#define OWS2  98304
#define OWH1  114688
#define OWH2  147456
#define OWV1  163840
#define OWV2  212992
#define OWT1  229376
#define OWT2  245760

static __device__ __forceinline__ float bf2f(u16 v){
  u32t x = ((u32t)v) << 16; float f; __builtin_memcpy(&f, &x, 4); return f;
}
static __device__ __forceinline__ u16 f2bf(float f){
  u32t x; __builtin_memcpy(&x, &f, 4);
  return (u16)((x + 0x7FFFu + ((x >> 16) & 1u)) >> 16);   // RNE
}

static __device__ __forceinline__ void zacc(f16v* acc){
#pragma unroll
  for (int i = 0; i < 16; ++i){ acc[0][i] = 0.f; acc[1][i] = 0.f; }
}

// GEMM: [64 rows x 32 cols-per-wave] += A[64][K] @ W[K][128], bf16 MFMA.
template<int K>
static __device__ __forceinline__ void gemm64(const u16* A, int astride, int aofs,
                                              const u16* __restrict__ WT, int Kp,
                                              int lane, int ct, f16v* acc)
{
  const int col = ct * 32 + (lane & 31);
  const int kh  = (lane >> 5) * 8;
  const u16* __restrict__ w  = WT + (size_t)col * Kp + kh;
  const u16* a0 = A + (lane & 31) * astride + aofs + kh;
  const u16* a1 = a0 + 32 * astride;
#pragma unroll 2
  for (int k = 0; k < K; k += 16){
    s8v b  = *(const s8v*)(w + k);
    s8v x0 = *(const s8v*)(a0 + k);
    s8v x1 = *(const s8v*)(a1 + k);
    acc[0] = __builtin_amdgcn_mfma_f32_32x32x16_bf16(x0, b, acc[0], 0, 0, 0);
    acc[1] = __builtin_amdgcn_mfma_f32_32x32x16_bf16(x1, b, acc[1], 0, 0, 0);
  }
}

// C/D layout: col = lane&31, row = (reg&3)+8*(reg>>2)+4*(lane>>5)  (+32 for acc[1])
static __device__ __forceinline__ void store_acc(const f16v* acc, u16* dst, int dstride, int dofs,
                                                 const float* __restrict__ bias, int act,
                                                 int lane, int ct)
{
  const int col = ct * 32 + (lane & 31);
  const float b = bias[col];
#pragma unroll
  for (int rt = 0; rt < 2; ++rt){
#pragma unroll
    for (int r = 0; r < 16; ++r){
      float x = acc[rt][r] + b;
      if (act) x = x / (1.f + __expf(-x));        // SiLU
      const int row = rt * 32 + (r & 3) + 8 * (r >> 2) + 4 * (lane >> 5);
      dst[row * dstride + dofs + col] = f2bf(x);
    }
  }
}

// ======================= weight prep =======================
struct WDesc { const float* src; int K; int dstoff; int Kp; };
struct WTab  { WDesc w[11]; };

__global__ void k_prep(WTab tab, u16* __restrict__ WT)
{
  const WDesc d = tab.w[blockIdx.y];
  const int total = 128 * d.Kp;
  const int idx = blockIdx.x * 256 + threadIdx.x;
  if (idx >= total) return;
  const int n = idx / d.Kp;
  const int k = idx - n * d.Kp;
  WT[d.dstoff + idx] = (k < d.K) ? f2bf(d.src[(size_t)k * 128 + n]) : (u16)0;
}

// ======================= CSR build =======================
__global__ void k_hist(const int* __restrict__ eidx, int* __restrict__ cnt)
{
  const int e = blockIdx.x * 256 + threadIdx.x;
  if (e < NE) atomicAdd(cnt + eidx[NE + e], 1);
}

__global__ void k_scan(const int* __restrict__ cnt, int* __restrict__ ptr, int* __restrict__ tail)
{
  __shared__ int part[1024];
  const int t = threadIdx.x;
  int s = 0;
  int loc[25];
#pragma unroll
  for (int q = 0; q < 25; ++q){
    const int i = t * 25 + q;
    loc[q] = (i < NN) ? cnt[i] : 0;
    s += loc[q];
  }
  part[t] = s;
  __syncthreads();
  for (int off = 1; off < 1024; off <<= 1){
    int v = (t >= off) ? part[t - off] : 0;
    __syncthreads();
    part[t] += v;
    __syncthreads();
  }
  int run = part[t] - s;   // exclusive base for this thread
#pragma unroll
  for (int q = 0; q < 25; ++q){
    const int i = t * 25 + q;
    if (i < NN){ ptr[i] = run; tail[i] = run; run += loc[q]; }
  }
  if (t == 1023) ptr[NN] = NE;
}

__global__ void k_scatter(const int* __restrict__ eidx, int* __restrict__ tail,
                          int* __restrict__ perm)
{
  const int e = blockIdx.x * 256 + threadIdx.x;
  if (e < NE){
    const int pos = atomicAdd(tail + eidx[NE + e], 1);
    perm[pos] = e;
  }
}

// ======================= f = species @ Wa + ba =======================
__global__ void __launch_bounds__(256, 2) k_f(const float* __restrict__ species,
                                              const u16* __restrict__ WT,
                                              const float* __restrict__ ba,
                                              u16* __restrict__ fbf)
{
  __shared__ u16 S[64 * 136];
  __shared__ u16 H[64 * 136];
  const int tid = threadIdx.x, lane = tid & 63, wid = tid >> 6;
  const int n0 = blockIdx.x * 64;
  const int rem = (NN - n0) < 64 ? (NN - n0) : 64;
  {
    const int row = tid >> 2, sub = tid & 3;
    const bool ok = row < rem;
    const float* src = species + (size_t)(n0 + row) * 100;
    for (int c = sub * 32; c < sub * 32 + 32; ++c)
      S[row * 136 + c] = (ok && c < 100) ? f2bf(src[c]) : (u16)0;
  }
  __syncthreads();
  f16v acc[2];
  zacc(acc);
  gemm64<128>(S, 136, 0, WT + OWA, 128, lane, wid, acc);
  store_acc(acc, H, 136, 0, ba, 0, lane, wid);
  __syncthreads();
#pragma unroll
  for (int it = 0; it < 8; ++it){
    const int row = it * 8 + (tid >> 5);
    if (row < rem){
      const int c4 = (tid & 31) * 4;
      uint2 v = *(const uint2*)(&H[row * 136 + c4]);
      *(uint2*)(fbf + (size_t)(n0 + row) * 128 + c4) = v;
    }
  }
}

// ======================= edge kernel (no atomics) =======================
__global__ void __launch_bounds__(256, 2) k_edge(
    const u16* __restrict__ fbf, const int* __restrict__ eidx,
    const float* __restrict__ eattr,
    const u16* __restrict__ WT,
    const float* __restrict__ bb1, const float* __restrict__ bb2,
    const float* __restrict__ bs1, const float* __restrict__ bs2,
    const float* __restrict__ bv1, const float* __restrict__ bv2,
    u16* __restrict__ msgbuf, u16* __restrict__ mvbuf)
{
  __shared__ u16 E[64 * 392];
  __shared__ u16 H[64 * 136];
  const int tid = threadIdx.x, lane = tid & 63, wid = tid >> 6;
  const int e0 = blockIdx.x * 64;

  // ---- stage f_i, f_j (bf16 gather), X0 = f2bf(edge_attr) (pad 120->128)
  {
    const int row = tid >> 2, sub = tid & 3;
    const int ii = eidx[e0 + row];
    const int jj = eidx[NE + e0 + row];
    const uint4* si = (const uint4*)(fbf + (size_t)ii * 128 + sub * 32);
    const uint4* sj = (const uint4*)(fbf + (size_t)jj * 128 + sub * 32);
    uint4* di = (uint4*)(&E[row * 392 + sub * 32]);
    uint4* dj = (uint4*)(&E[row * 392 + 128 + sub * 32]);
#pragma unroll
    for (int q = 0; q < 4; ++q){ di[q] = si[q]; dj[q] = sj[q]; }
  }
  if (tid < 128){
    const int row = tid >> 1, u = tid & 1;
    const float* s = eattr + (size_t)(e0 + row) * 120 + u * 60;
#pragma unroll
    for (int q = 0; q < 15; ++q){
      float4 v = *(const float4*)(s + q * 4);
      ushort4 p;
      p.x = f2bf(v.x); p.y = f2bf(v.y); p.z = f2bf(v.z); p.w = f2bf(v.w);
      *(ushort4*)(&E[row * 392 + 256 + u * 60 + q * 4]) = p;
    }
    ushort4 z; z.x = z.y = z.z = z.w = 0;
    *(ushort4*)(&E[row * 392 + 376 + u * 4]) = z;
  }
  __syncthreads();

  f16v acc[2];

  // ---- ea = silu(X0@Wb1+bb1)@Wb2 + bb2  (bf16, kept in E only)
  zacc(acc);
  gemm64<128>(E, 392, 256, WT + OWB1, 128, lane, wid, acc);
  store_acc(acc, H, 136, 0, bb1, 1, lane, wid);
  __syncthreads();
  zacc(acc);
  gemm64<128>(H, 136, 0, WT + OWB2, 128, lane, wid, acc);
  __syncthreads();
  store_acc(acc, E, 392, 256, bb2, 0, lane, wid);
  __syncthreads();

  // ---- msg = (silu(e@Ws1+bs1)@Ws2+bs2) * f_i  -> msgbuf bf16
  zacc(acc);
  gemm64<384>(E, 392, 0, WT + OWS1, 384, lane, wid, acc);
  store_acc(acc, H, 136, 0, bs1, 1, lane, wid);
  __syncthreads();
  zacc(acc);
  gemm64<128>(H, 136, 0, WT + OWS2, 128, lane, wid, acc);
  __syncthreads();
  store_acc(acc, H, 136, 0, bs2, 0, lane, wid);
  __syncthreads();
#pragma unroll
  for (int it = 0; it < 8; ++it){
    const int row = it * 8 + (tid >> 5);
    const int c4 = (tid & 31) * 4;
    uint2 hm = *(const uint2*)(&H[row * 136 + c4]);
    uint2 fi = *(const uint2*)(&E[row * 392 + c4]);
    const u16* hp = (const u16*)&hm;
    const u16* fp = (const u16*)&fi;
    ushort4 p;
    p.x = f2bf(bf2f(hp[0]) * bf2f(fp[0]));
    p.y = f2bf(bf2f(hp[1]) * bf2f(fp[1]));
    p.z = f2bf(bf2f(hp[2]) * bf2f(fp[2]));
    p.w = f2bf(bf2f(hp[3]) * bf2f(fp[3]));
    *(ushort4*)(msgbuf + (size_t)(e0 + row) * 128 + c4) = p;
  }
  __syncthreads();

  // ---- mv = silu(e@Wv1+bv1)@Wv2+bv2  -> mvbuf bf16
  zacc(acc);
  gemm64<384>(E, 392, 0, WT + OWV1, 384, lane, wid, acc);
  store_acc(acc, H, 136, 0, bv1, 1, lane, wid);
  __syncthreads();
  zacc(acc);
  gemm64<128>(H, 136, 0, WT + OWV2, 128, lane, wid, acc);
  __syncthreads();
  store_acc(acc, H, 136, 0, bv2, 0, lane, wid);
  __syncthreads();
#pragma unroll
  for (int it = 0; it < 8; ++it){
    const int row = it * 8 + (tid >> 5);
    const int c4 = (tid & 31) * 4;
    uint2 v = *(const uint2*)(&H[row * 136 + c4]);
    *(uint2*)(mvbuf + (size_t)(e0 + row) * 128 + c4) = v;
  }
}

// ======================= segment-sum aggregation (1 wave / node) =======================
__global__ void __launch_bounds__(256, 4) k_agg(
    const int* __restrict__ ptr, const int* __restrict__ perm,
    const u16* __restrict__ msgbuf, const u16* __restrict__ mvbuf,
    const float* __restrict__ evec,
    u16* __restrict__ aggbf, float* __restrict__ v0out)
{
  const int tid = threadIdx.x, lane = tid & 63, wid = tid >> 6;
  const int n = blockIdx.x * 4 + wid;
  const int kb = ptr[n], ke = ptr[n + 1];

  float a0 = 0.f, a1 = 0.f;
  float v00 = 0.f, v01 = 0.f, v02 = 0.f, v10 = 0.f, v11 = 0.f, v12 = 0.f;

  const uint* mb = (const uint*)msgbuf;
  const uint* vb = (const uint*)mvbuf;
  for (int k = kb; k < ke; ++k){
    const int e = perm[k];
    const uint m2 = mb[(size_t)e * 64 + lane];
    const uint w2 = vb[(size_t)e * 64 + lane];
    const float ex = evec[(size_t)e * 3 + 0];
    const float ey = evec[(size_t)e * 3 + 1];
    const float ez = evec[(size_t)e * 3 + 2];
    a0 += bf2f((u16)(m2 & 0xFFFF));
    a1 += bf2f((u16)(m2 >> 16));
    const float m0 = bf2f((u16)(w2 & 0xFFFF));
    const float m1 = bf2f((u16)(w2 >> 16));
    v00 += m0 * ex; v01 += m0 * ey; v02 += m0 * ez;
    v10 += m1 * ex; v11 += m1 * ey; v12 += m1 * ez;
  }
  const uint packed = (uint)f2bf(a0) | ((uint)f2bf(a1) << 16);
  ((uint*)aggbf)[(size_t)n * 64 + lane] = packed;
  float* vd = v0out + (size_t)n * 384 + lane * 6;
  float2 p0; p0.x = v00; p0.y = v01;
  float2 p1; p1.x = v02; p1.y = v10;
  float2 p2; p2.x = v11; p2.y = v12;
  *(float2*)(vd + 0) = p0;
  *(float2*)(vd + 2) = p1;
  *(float2*)(vd + 4) = p2;
}

// ======================= ea recompute (writes f32 over scratch) =======================
__global__ void __launch_bounds__(256, 2) k_edge2(
    const float* __restrict__ eattr, const u16* __restrict__ WT,
    const float* __restrict__ bb1, const float* __restrict__ bb2,
    float* __restrict__ ea_out)
{
  __shared__ u16 X[64 * 136];
  __shared__ u16 H[64 * 136];
  const int tid = threadIdx.x, lane = tid & 63, wid = tid >> 6;
  const int e0 = blockIdx.x * 64;

  if (tid < 128){
    const int row = tid >> 1, u = tid & 1;
    const float* s = eattr + (size_t)(e0 + row) * 120 + u * 60;
#pragma unroll
    for (int q = 0; q < 15; ++q){
      float4 v = *(const float4*)(s + q * 4);
      ushort4 p;
      p.x = f2bf(v.x); p.y = f2bf(v.y); p.z = f2bf(v.z); p.w = f2bf(v.w);
      *(ushort4*)(&X[row * 136 + u * 60 + q * 4]) = p;
    }
    ushort4 z; z.x = z.y = z.z = z.w = 0;
    *(ushort4*)(&X[row * 136 + 120 + u * 4]) = z;
  }
  __syncthreads();

  f16v acc[2];
  zacc(acc);
  gemm64<128>(X, 136, 0, WT + OWB1, 128, lane, wid, acc);
  store_acc(acc, H, 136, 0, bb1, 1, lane, wid);
  __syncthreads();
  zacc(acc);
  gemm64<128>(H, 136, 0, WT + OWB2, 128, lane, wid, acc);
  __syncthreads();
  store_acc(acc, X, 136, 0, bb2, 0, lane, wid);
  __syncthreads();
#pragma unroll
  for (int it = 0; it < 8; ++it){
    const int row = it * 8 + (tid >> 5);
    const int c4 = (tid & 31) * 4;
    uint2 v = *(const uint2*)(&X[row * 136 + c4]);
    const u16* hp = (const u16*)&v;
    float4 o;
    o.x = bf2f(hp[0]); o.y = bf2f(hp[1]); o.z = bf2f(hp[2]); o.w = bf2f(hp[3]);
    *(float4*)(ea_out + (size_t)(e0 + row) * 128 + c4) = o;
  }
}

// ======================= node kernel: h0 =======================
__global__ void __launch_bounds__(256, 2) k_node(
    const u16* __restrict__ fbf, const u16* __restrict__ aggbf,
    const float* __restrict__ tin, const float* __restrict__ brff,
    const u16* __restrict__ WT,
    const float* __restrict__ bh1, const float* __restrict__ bh2,
    const float* __restrict__ bt1, const float* __restrict__ bt2,
    float* __restrict__ out)
{
  __shared__ u16 E2[64 * 264];   // [f | agg]
  __shared__ u16 RF[64 * 136];   // rff = [cos | sin]
  __shared__ u16 H[64 * 136];
  const int tid = threadIdx.x, lane = tid & 63, wid = tid >> 6;
  const int n0 = blockIdx.x * 64;
  const int rem = (NN - n0) < 64 ? (NN - n0) : 64;

  {
    const int row = tid >> 2, sub = tid & 3;
    if (row < rem){
      const uint4* s = (const uint4*)(fbf + (size_t)(n0 + row) * 128 + sub * 32);
      const uint4* a = (const uint4*)(aggbf + (size_t)(n0 + row) * 128 + sub * 32);
      uint4* d  = (uint4*)(&E2[row * 264 + sub * 32]);
      uint4* d2 = (uint4*)(&E2[row * 264 + 128 + sub * 32]);
#pragma unroll
      for (int q = 0; q < 4; ++q){ d[q] = s[q]; d2[q] = a[q]; }
    } else {
      uint4 z; z.x = z.y = z.z = z.w = 0;
      uint4* d  = (uint4*)(&E2[row * 264 + sub * 32]);
      uint4* d2 = (uint4*)(&E2[row * 264 + 128 + sub * 32]);
#pragma unroll
      for (int q = 0; q < 4; ++q){ d[q] = z; d2[q] = z; }
    }
  }
  {
    const int row = tid >> 2, qq = tid & 3;
    if (row < rem){
      const float tv = tin[n0 + row];
      for (int c = qq * 16; c < qq * 16 + 16; ++c){
        const float p = 6.283185307179586f * tv * brff[c];
        RF[row * 136 + c]      = f2bf(cosf(p));
        RF[row * 136 + 64 + c] = f2bf(sinf(p));
      }
    } else {
      for (int c = qq * 16; c < qq * 16 + 16; ++c){
        RF[row * 136 + c] = 0; RF[row * 136 + 64 + c] = 0;
      }
    }
  }
  __syncthreads();

  f16v acc[2], acch[2];
  zacc(acc);
  gemm64<256>(E2, 264, 0, WT + OWH1, 256, lane, wid, acc);
  store_acc(acc, H, 136, 0, bh1, 1, lane, wid);
  __syncthreads();
  zacc(acch);
  gemm64<128>(H, 136, 0, WT + OWH2, 128, lane, wid, acch);
  __syncthreads();
  zacc(acc);
  gemm64<128>(RF, 136, 0, WT + OWT1, 128, lane, wid, acc);
  store_acc(acc, H, 136, 0, bt1, 1, lane, wid);
  __syncthreads();
  gemm64<128>(H, 136, 0, WT + OWT2, 128, lane, wid, acch);  // accumulate
  __syncthreads();
  {
    const int col = wid * 32 + (lane & 31);
    const float b = bh2[col] + bt2[col];
#pragma unroll
    for (int rt = 0; rt < 2; ++rt)
#pragma unroll
      for (int r = 0; r < 16; ++r){
        const int row = rt * 32 + (r & 3) + 8 * (r >> 2) + 4 * (lane >> 5);
        H[row * 136 + col] = f2bf(acch[rt][r] + b);
      }
  }
  __syncthreads();
#pragma unroll
  for (int it = 0; it < 8; ++it){
    const int row = it * 8 + (tid >> 5);
    if (row < rem){
      const int c4 = (tid & 31) * 4;
      uint2 v = *(const uint2*)(&H[row * 136 + c4]);
      const u16* hp = (const u16*)&v;
      float4 o;
      o.x = bf2f(hp[0]); o.y = bf2f(hp[1]); o.z = bf2f(hp[2]); o.w = bf2f(hp[3]);
      *(float4*)(out + (size_t)(n0 + row) * 128 + c4) = o;
    }
  }
}

// ======================= launcher =======================
extern "C" void kernel_launch(void* const* d_in, const int* in_sizes, int n_in,
                              void* d_out, int out_size, void* d_ws, size_t ws_size,
                              hipStream_t stream)
{
  (void)in_sizes; (void)n_in; (void)out_size;
  const float* species = (const float*)d_in[0];
  const int*   eidx    = (const int*)d_in[1];
  const float* eattr   = (const float*)d_in[2];
  const float* evec    = (const float*)d_in[3];
  const float* tin     = (const float*)d_in[4];
  const float* Wa  = (const float*)d_in[5];  const float* ba  = (const float*)d_in[6];
  const float* Wb1 = (const float*)d_in[7];  const float* bb1 = (const float*)d_in[8];
  const float* Wb2 = (const float*)d_in[9];  const float* bb2 = (const float*)d_in[10];
  const float* Ws1 = (const float*)d_in[11]; const float* bs1 = (const float*)d_in[12];
  const float* Ws2 = (const float*)d_in[13]; const float* bs2 = (const float*)d_in[14];
  const float* Wh1 = (const float*)d_in[15]; const float* bh1 = (const float*)d_in[16];
  const float* Wh2 = (const float*)d_in[17]; const float* bh2 = (const float*)d_in[18];
  const float* Wv1 = (const float*)d_in[19]; const float* bv1 = (const float*)d_in[20];
  const float* Wv2 = (const float*)d_in[21]; const float* bv2 = (const float*)d_in[22];
  const float* brff= (const float*)d_in[23];
  const float* Wt1 = (const float*)d_in[24]; const float* bt1 = (const float*)d_in[25];
  const float* Wt2 = (const float*)d_in[26]; const float* bt2 = (const float*)d_in[27];

  if (ws_size < (size_t)WS_NEED) return;

  u16*  WT    = (u16*)d_ws;
  u16*  fbf   = (u16*)((char*)d_ws + OFF_FBF_B);
  u16*  aggbf = (u16*)((char*)d_ws + OFF_AGG_B);
  int*  ptr   = (int*)((char*)d_ws + OFF_PTR_B);
  int*  tail  = (int*)((char*)d_ws + OFF_TAIL_B);
  int*  perm  = (int*)((char*)d_ws + OFF_PERM_B);

  float* out = (float*)d_out;
  float* v0  = out + 3200000;                 // v0 region
  float* eao = out + 12800000;                // ea region (also scratch)
  u16*   msgbuf = (u16*)eao;                  // 102.4 MB
  u16*   mvbuf  = msgbuf + 51200000;          // 102.4 MB

  // zero histogram counters (tail doubles as counts during hist)
  hipMemsetAsync((char*)d_ws + OFF_TAIL_B, 0, 100000, stream);

  WTab tab;
  tab.w[0]  = { Wa , 100, OWA , 128 };
  tab.w[1]  = { Wb1, 120, OWB1, 128 };
  tab.w[2]  = { Wb2, 128, OWB2, 128 };
  tab.w[3]  = { Ws1, 384, OWS1, 384 };
  tab.w[4]  = { Ws2, 128, OWS2, 128 };
  tab.w[5]  = { Wh1, 256, OWH1, 256 };
  tab.w[6]  = { Wh2, 128, OWH2, 128 };
  tab.w[7]  = { Wv1, 384, OWV1, 384 };
  tab.w[8]  = { Wv2, 128, OWV2, 128 };
  tab.w[9]  = { Wt1, 128, OWT1, 128 };
  tab.w[10] = { Wt2, 128, OWT2, 128 };
  hipLaunchKernelGGL(k_prep, dim3(192, 11), dim3(256), 0, stream, tab, WT);

  hipLaunchKernelGGL(k_f, dim3(391), dim3(256), 0, stream, species, WT, ba, fbf);

  // CSR build
  hipLaunchKernelGGL(k_hist,    dim3(1563), dim3(256),  0, stream, eidx, tail);
  hipLaunchKernelGGL(k_scan,    dim3(1),    dim3(1024), 0, stream, tail, ptr, tail);
  hipLaunchKernelGGL(k_scatter, dim3(1563), dim3(256),  0, stream, eidx, tail, perm);

  // edge MLPs -> msg/mv buffers (in d_out ea region)
  hipLaunchKernelGGL(k_edge, dim3(6250), dim3(256), 0, stream,
                     fbf, eidx, eattr, WT, bb1, bb2, bs1, bs2, bv1, bv2,
                     msgbuf, mvbuf);

  // segment sums -> aggbf + v0
  hipLaunchKernelGGL(k_agg, dim3(6250), dim3(256), 0, stream,
                     ptr, perm, msgbuf, mvbuf, evec, aggbf, v0);

  // node MLP -> h0
  hipLaunchKernelGGL(k_node, dim3(391), dim3(256), 0, stream,
                     fbf, aggbf, tin, brff, WT, bh1, bh2, bt1, bt2, out);

  // recompute ea and overwrite scratch with final f32 output
  hipLaunchKernelGGL(k_edge2, dim3(6250), dim3(256), 0, stream,
                     eattr, WT, bb1, bb2, eao);
}